// Round 14
// baseline (97.586 us; speedup 1.0000x reference)
//
#include <hip/hip_runtime.h>

// B=256, IN_F=512, K_INT=75, OUT_F=64
// ws: Mt2[z][o][k][b] fp32 @ 0          (2 x 4,915,200 B) — K-split slabs
//     Tb[k*64+o][f] bf16   @ 9,830,400  (4,915,200 B)
//     xb[b][f] bf16        @ 14,745,600 (  262,144 B)
//
// R14 = R13 byte-identical kernels; cvt_all and md_gemm_mfma launched 3x each
// (idempotent) to measure c+g = (dur - 54.2)/2.

typedef __attribute__((ext_vector_type(8))) short bf16x8;
typedef __attribute__((ext_vector_type(4))) float f32x4;
typedef unsigned short u16;
typedef unsigned int u32;

__device__ inline u16 f2bf(float f) {            // RNE float->bf16 bits
  u32 u = __float_as_uint(f);
  return (u16)((u + 0x7FFFu + ((u >> 16) & 1u)) >> 16);
}
__device__ inline float bflo(u32 u) { return __uint_as_float(u << 16); }
__device__ inline float bfhi(u32 u) { return __uint_as_float(u & 0xFFFF0000u); }

// ---------- fused convert (verbatim R11): bid<600 T-tiles, >=600 x-chunks ----------
__global__ __launch_bounds__(256) void cvt_all(const float* __restrict__ x,
                                               const float* __restrict__ T,
                                               u16* __restrict__ xb,
                                               u16* __restrict__ Tb) {
  const int bid = blockIdx.x;
  const int tid = threadIdx.x;

  if (bid >= 600) {
    const int i = (bid - 600) * 256 + tid;
    const float4* x4 = reinterpret_cast<const float4*>(x);
    const float4 v0 = x4[i * 2], v1 = x4[i * 2 + 1];
    uint4 o;
    o.x = (u32)f2bf(v0.x) | ((u32)f2bf(v0.y) << 16);
    o.y = (u32)f2bf(v0.z) | ((u32)f2bf(v0.w) << 16);
    o.z = (u32)f2bf(v1.x) | ((u32)f2bf(v1.y) << 16);
    o.w = (u32)f2bf(v1.z) | ((u32)f2bf(v1.w) << 16);
    *reinterpret_cast<uint4*>(xb + i * 8) = o;
    return;
  }

  const int f0 = (bid & 7) << 6;
  const int k = bid >> 3;            // 0..74
  __shared__ float tile[64][65];

  const float4* T4 = reinterpret_cast<const float4*>(T);
  const int r = tid >> 2;
  const int c = tid & 3;
#pragma unroll
  for (int h = 0; h < 4; ++h) {
    const int q = c + (h << 2);
    const float4 v = T4[(f0 + r) * 1200 + k * 16 + q];
    tile[r][(q << 2) + 0] = v.x;
    tile[r][(q << 2) + 1] = v.y;
    tile[r][(q << 2) + 2] = v.z;
    tile[r][(q << 2) + 3] = v.w;
  }
  __syncthreads();

  const int w = tid >> 2;
  u16 us[16];
#pragma unroll
  for (int j = 0; j < 16; ++j) us[j] = f2bf(tile[(c << 4) + j][w]);
  uint4 p0, p1;
  p0.x = (u32)us[0] | ((u32)us[1] << 16);
  p0.y = (u32)us[2] | ((u32)us[3] << 16);
  p0.z = (u32)us[4] | ((u32)us[5] << 16);
  p0.w = (u32)us[6] | ((u32)us[7] << 16);
  p1.x = (u32)us[8] | ((u32)us[9] << 16);
  p1.y = (u32)us[10] | ((u32)us[11] << 16);
  p1.z = (u32)us[12] | ((u32)us[13] << 16);
  p1.w = (u32)us[14] | ((u32)us[15] << 16);
  uint4* dst = reinterpret_cast<uint4*>(Tb + ((k << 6) + w) * 512 + f0 + (c << 4));
  dst[0] = p0;
  dst[1] = p1;
}

// ---------- MFMA GEMM, K-split x2 (verbatim R11) ----------
__global__ __launch_bounds__(256) void md_gemm_mfma(const u16* __restrict__ Tb,
                                                    const u16* __restrict__ xb,
                                                    float* __restrict__ Mt2) {
  const int tid = threadIdx.x;
  const int l = tid & 63, w = tid >> 6;
  const int n0 = (blockIdx.x << 6) + ((w >> 1) << 5);
  const int b0 = (blockIdx.y << 6) + ((w & 1) << 5);
  const int z = blockIdx.z;          // K-half: f in [z*256, z*256+256)
  const int lr = l & 15;
  const int ko = (l >> 4) << 3;

  const u16* pa0 = Tb + (n0 + lr) * 512 + z * 256 + ko;
  const u16* pa1 = pa0 + 16 * 512;
  const u16* pb0 = xb + (b0 + lr) * 512 + z * 256 + ko;
  const u16* pb1 = pb0 + 16 * 512;

  f32x4 d00 = {0.f, 0.f, 0.f, 0.f}, d01 = d00, d10 = d00, d11 = d00;

#pragma unroll 4
  for (int kk = 0; kk < 8; ++kk) {
    const int off = kk << 5;
    const bf16x8 a0 = *reinterpret_cast<const bf16x8*>(pa0 + off);
    const bf16x8 a1 = *reinterpret_cast<const bf16x8*>(pa1 + off);
    const bf16x8 f0 = *reinterpret_cast<const bf16x8*>(pb0 + off);
    const bf16x8 f1 = *reinterpret_cast<const bf16x8*>(pb1 + off);
    d00 = __builtin_amdgcn_mfma_f32_16x16x32_bf16(a0, f0, d00, 0, 0, 0);
    d01 = __builtin_amdgcn_mfma_f32_16x16x32_bf16(a0, f1, d01, 0, 0, 0);
    d10 = __builtin_amdgcn_mfma_f32_16x16x32_bf16(a1, f0, d10, 0, 0, 0);
    d11 = __builtin_amdgcn_mfma_f32_16x16x32_bf16(a1, f1, d11, 0, 0, 0);
  }

  float* Mt = Mt2 + z * 1228800;     // slab
#pragma unroll
  for (int r = 0; r < 4; ++r) {
    const int row = ((l >> 4) << 2) + r;
    {
      const int n = n0 + row;
      float* base = Mt + (n & 63) * 19200 + (n >> 6) * 256;
      base[b0 + lr] = d00[r];
      base[b0 + 16 + lr] = d01[r];
    }
    {
      const int n = n0 + 16 + row;
      float* base = Mt + (n & 63) * 19200 + (n >> 6) * 256;
      base[b0 + lr] = d10[r];
      base[b0 + 16 + lr] = d11[r];
    }
  }
}

// ---------- pairwise v4 (verbatim R13) ----------
__global__ __launch_bounds__(512) void md_pair4(const float* __restrict__ Mt2,
                                                float* __restrict__ out) {
  const int bid = blockIdx.x;
  const int o = bid & 63;
  const int it = bid >> 6;             // 0..7
  const int ibase = it << 5;           // 32 i per block
  const int tid = threadIdx.x;
  const int is = tid & 15;             // i-slot (2 i's)
  const int jg = tid >> 4;             // j-group (8 j's), 0..31

  __shared__ alignas(16) u16 MjB[38 * 256];    // 19,456 B  bf16 j-panel
  __shared__ alignas(16) float MiF[38 * 32];   //  4,864 B  f32 i-panel

  const float* M0 = Mt2 + o * 19200;           // slab 0
  const float* M1 = M0 + 1228800;              // slab 1

  float d[2][8];
#pragma unroll
  for (int a = 0; a < 2; ++a)
#pragma unroll
    for (int b = 0; b < 8; ++b) d[a][b] = 0.0f;

  for (int h = 0; h < 2; ++h) {
    const int kbase = h * 38;
    __syncthreads();                   // prior reads done before overwrite
    for (int idx = tid; idx < 38 * 64; idx += 512) {
      const int kk = idx >> 6, q = idx & 63;
      const int gk = kbase + kk;
      uint2 p;
      if (gk < 75) {
        const int goff = gk * 256 + (q << 2);
        const float4 v0 = *reinterpret_cast<const float4*>(M0 + goff);
        const float4 v1 = *reinterpret_cast<const float4*>(M1 + goff);
        p.x = (u32)f2bf(v0.x + v1.x) | ((u32)f2bf(v0.y + v1.y) << 16);
        p.y = (u32)f2bf(v0.z + v1.z) | ((u32)f2bf(v0.w + v1.w) << 16);
      } else {
        p = make_uint2(0u, 0u);
      }
      *reinterpret_cast<uint2*>(MjB + kk * 256 + (q << 2)) = p;
    }
    for (int idx = tid; idx < 38 * 32; idx += 512) {
      const int kk = idx >> 5, ii = idx & 31;
      const int gk = kbase + kk;
      const int goff = gk * 256 + ibase + ii;
      MiF[kk * 32 + ii] = (gk < 75) ? (M0[goff] + M1[goff]) : 0.0f;
    }
    __syncthreads();

#pragma unroll 19
    for (int kk = 0; kk < 38; ++kk) {
      const float2 vi = *reinterpret_cast<const float2*>(MiF + kk * 32 + (is << 1));
      const uint4 ju = *reinterpret_cast<const uint4*>(MjB + kk * 256 + (jg << 3));
      const float ja[8] = {bflo(ju.x), bfhi(ju.x), bflo(ju.y), bfhi(ju.y),
                           bflo(ju.z), bfhi(ju.z), bflo(ju.w), bfhi(ju.w)};
#pragma unroll
      for (int b = 0; b < 8; ++b) {
        d[0][b] += __builtin_fabsf(ja[b] - vi.x);
        d[1][b] += __builtin_fabsf(ja[b] - vi.y);
      }
    }
  }

  float s[2];
#pragma unroll
  for (int a = 0; a < 2; ++a) {
    const int ia = ibase + (is << 1) + a;
    float t = 0.0f;
#pragma unroll
    for (int b = 0; b < 8; ++b) {
      const int j = (jg << 3) + b;
      const float e = __expf(-d[a][b]);
      t += (j == ia) ? 0.0f : e;               // skip self-term exactly
    }
    s[a] = t;
  }

  __syncthreads();
  float* red = reinterpret_cast<float*>(MjB);  // red[i_local 32][jg 32], stride 33
  red[((is << 1) + 0) * 33 + jg] = s[0];
  red[((is << 1) + 1) * 33 + jg] = s[1];
  __syncthreads();
  if (tid < 32) {
    float t = 0.0f;
#pragma unroll
    for (int g = 0; g < 32; ++g) t += red[tid * 33 + g];
    out[(ibase + tid) * 64 + o] = t;           // self-term already excluded
  }
}

extern "C" void kernel_launch(void* const* d_in, const int* in_sizes, int n_in,
                              void* d_out, int out_size, void* d_ws, size_t ws_size,
                              hipStream_t stream) {
  const float* x = (const float*)d_in[0];   // [256,512]
  const float* T = (const float*)d_in[1];   // [512,75,64]
  float* out = (float*)d_out;               // [256,64]

  char* ws = (char*)d_ws;
  float* Mt2 = (float*)ws;                  // 2 x 4,915,200 B
  u16* Tb = (u16*)(ws + 9830400);           // 4,915,200 B
  u16* xb = (u16*)(ws + 14745600);          //   262,144 B

  // --- measurement: 3x cvt + 3x gemm (idempotent); c+g = (dur - 54.2)/2 ---
  cvt_all<<<664, 256, 0, stream>>>(x, T, xb, Tb);
  md_gemm_mfma<<<dim3(75, 4, 2), 256, 0, stream>>>(Tb, xb, Mt2);
  cvt_all<<<664, 256, 0, stream>>>(x, T, xb, Tb);
  md_gemm_mfma<<<dim3(75, 4, 2), 256, 0, stream>>>(Tb, xb, Mt2);
  cvt_all<<<664, 256, 0, stream>>>(x, T, xb, Tb);
  md_gemm_mfma<<<dim3(75, 4, 2), 256, 0, stream>>>(Tb, xb, Mt2);
  md_pair4<<<512, 512, 0, stream>>>(Mt2, out);
}

// Round 15
// 50.353 us; speedup vs baseline: 1.9380x; 1.9380x over previous
//
#include <hip/hip_runtime.h>

// B=256, IN_F=512, K_INT=75, OUT_F=64
// ws: Mt2[z][o][k][b] fp32 @ 0 (2 x 4,915,200 B) — K-split slabs. Nothing else.

typedef __attribute__((ext_vector_type(8))) short bf16x8;
typedef __attribute__((ext_vector_type(4))) float f32x4;
typedef unsigned short u16;
typedef unsigned int u32;

__device__ inline u16 f2bf(float f) {            // RNE float->bf16 bits (pair staging)
  u32 u = __float_as_uint(f);
  return (u16)((u + 0x7FFFu + ((u >> 16) & 1u)) >> 16);
}
__device__ inline short bftrunc(float f) {       // truncating cvt (gemm fragments)
  return (short)(__float_as_uint(f) >> 16);
}
__device__ inline float bflo(u32 u) { return __uint_as_float(u << 16); }
__device__ inline float bfhi(u32 u) { return __uint_as_float(u & 0xFFFF0000u); }

// ---------- MFMA GEMM from raw fp32 inputs: Mt2[z][o][k][b] = sum_f x[b][f]*T[f][k][o] ----------
// Grid (75, 4, 2), 256 thr = 4 waves (2n x 2b). In-register bf16 truncation.
// A-gather: T[f][kc][o], 8 dwords/frag, stride 4800; 16-lane groups hit 64B segments.
// B-load: x[b][f..f+8] = 2 float4, contiguous.
__global__ __launch_bounds__(256) void md_gemm_direct(const float* __restrict__ x,
                                                      const float* __restrict__ T,
                                                      float* __restrict__ Mt2) {
  const int tid = threadIdx.x;
  const int l = tid & 63, w = tid >> 6;
  const int bx = blockIdx.x;               // kc 0..74
  const int b0 = (blockIdx.y << 6) + ((w & 1) << 5);
  const int z = blockIdx.z;                // K-half: f in [z*256, z*256+256)
  const int lr = l & 15;
  const int ko = (l >> 4) << 3;            // 8 contiguous f per lane group
  const int oh = (w >> 1) << 5;            // o-half base 0/32

  // A: T[(z*256+ko+e)*4800 + bx*64 + oh + lr]  (+16 in o for the second frag)
  const float* At = T + (z * 256 + ko) * 4800 + bx * 64 + oh + lr;
  // B: x[(b0+lr)*512 + z*256 + ko]             (+16*512 for the second frag)
  const float* Bx0 = x + (b0 + lr) * 512 + z * 256 + ko;
  const float* Bx1 = Bx0 + 16 * 512;

  f32x4 d00 = {0.f, 0.f, 0.f, 0.f}, d01 = d00, d10 = d00, d11 = d00;

#pragma unroll 2
  for (int kk = 0; kk < 8; ++kk) {
    bf16x8 a0, a1, f0, f1;
    const float* Ak = At + (kk << 5) * 4800;
#pragma unroll
    for (int e = 0; e < 8; ++e) {
      a0[e] = bftrunc(Ak[e * 4800]);         // o = oh+lr
      a1[e] = bftrunc(Ak[e * 4800 + 16]);    // o = oh+lr+16
    }
    const float4 b00 = *reinterpret_cast<const float4*>(Bx0 + (kk << 5));
    const float4 b01 = *reinterpret_cast<const float4*>(Bx0 + (kk << 5) + 4);
    const float4 b10 = *reinterpret_cast<const float4*>(Bx1 + (kk << 5));
    const float4 b11 = *reinterpret_cast<const float4*>(Bx1 + (kk << 5) + 4);
    f0[0] = bftrunc(b00.x); f0[1] = bftrunc(b00.y); f0[2] = bftrunc(b00.z); f0[3] = bftrunc(b00.w);
    f0[4] = bftrunc(b01.x); f0[5] = bftrunc(b01.y); f0[6] = bftrunc(b01.z); f0[7] = bftrunc(b01.w);
    f1[0] = bftrunc(b10.x); f1[1] = bftrunc(b10.y); f1[2] = bftrunc(b10.z); f1[3] = bftrunc(b10.w);
    f1[4] = bftrunc(b11.x); f1[5] = bftrunc(b11.y); f1[6] = bftrunc(b11.z); f1[7] = bftrunc(b11.w);

    d00 = __builtin_amdgcn_mfma_f32_16x16x32_bf16(a0, f0, d00, 0, 0, 0);
    d01 = __builtin_amdgcn_mfma_f32_16x16x32_bf16(a0, f1, d01, 0, 0, 0);
    d10 = __builtin_amdgcn_mfma_f32_16x16x32_bf16(a1, f0, d10, 0, 0, 0);
    d11 = __builtin_amdgcn_mfma_f32_16x16x32_bf16(a1, f1, d11, 0, 0, 0);
  }

  // store (verbatim R11 pattern): n = bx*64 + oh + {row, row+16}; Mt[o][k][b]
  float* Mt = Mt2 + z * 1228800;
  const int n0 = (bx << 6) + oh;
#pragma unroll
  for (int r = 0; r < 4; ++r) {
    const int row = ((l >> 4) << 2) + r;
    {
      const int n = n0 + row;
      float* base = Mt + (n & 63) * 19200 + (n >> 6) * 256;
      base[b0 + lr] = d00[r];
      base[b0 + 16 + lr] = d01[r];
    }
    {
      const int n = n0 + 16 + row;
      float* base = Mt + (n & 63) * 19200 + (n >> 6) * 256;
      base[b0 + lr] = d10[r];
      base[b0 + 16 + lr] = d11[r];
    }
  }
}

// ---------- pairwise v4 (verbatim R13): 512 thr, 2i x 8j, fixed-38 k-halves ----------
__global__ __launch_bounds__(512) void md_pair4(const float* __restrict__ Mt2,
                                                float* __restrict__ out) {
  const int bid = blockIdx.x;
  const int o = bid & 63;
  const int it = bid >> 6;             // 0..7
  const int ibase = it << 5;           // 32 i per block
  const int tid = threadIdx.x;
  const int is = tid & 15;             // i-slot (2 i's)
  const int jg = tid >> 4;             // j-group (8 j's), 0..31

  __shared__ alignas(16) u16 MjB[38 * 256];    // 19,456 B  bf16 j-panel
  __shared__ alignas(16) float MiF[38 * 32];   //  4,864 B  f32 i-panel

  const float* M0 = Mt2 + o * 19200;           // slab 0
  const float* M1 = M0 + 1228800;              // slab 1

  float d[2][8];
#pragma unroll
  for (int a = 0; a < 2; ++a)
#pragma unroll
    for (int b = 0; b < 8; ++b) d[a][b] = 0.0f;

  for (int h = 0; h < 2; ++h) {
    const int kbase = h * 38;
    __syncthreads();                   // prior reads done before overwrite
    for (int idx = tid; idx < 38 * 64; idx += 512) {
      const int kk = idx >> 6, q = idx & 63;
      const int gk = kbase + kk;
      uint2 p;
      if (gk < 75) {
        const int goff = gk * 256 + (q << 2);
        const float4 v0 = *reinterpret_cast<const float4*>(M0 + goff);
        const float4 v1 = *reinterpret_cast<const float4*>(M1 + goff);
        p.x = (u32)f2bf(v0.x + v1.x) | ((u32)f2bf(v0.y + v1.y) << 16);
        p.y = (u32)f2bf(v0.z + v1.z) | ((u32)f2bf(v0.w + v1.w) << 16);
      } else {
        p = make_uint2(0u, 0u);
      }
      *reinterpret_cast<uint2*>(MjB + kk * 256 + (q << 2)) = p;
    }
    for (int idx = tid; idx < 38 * 32; idx += 512) {
      const int kk = idx >> 5, ii = idx & 31;
      const int gk = kbase + kk;
      const int goff = gk * 256 + ibase + ii;
      MiF[kk * 32 + ii] = (gk < 75) ? (M0[goff] + M1[goff]) : 0.0f;
    }
    __syncthreads();

#pragma unroll 19
    for (int kk = 0; kk < 38; ++kk) {
      const float2 vi = *reinterpret_cast<const float2*>(MiF + kk * 32 + (is << 1));
      const uint4 ju = *reinterpret_cast<const uint4*>(MjB + kk * 256 + (jg << 3));
      const float ja[8] = {bflo(ju.x), bfhi(ju.x), bflo(ju.y), bfhi(ju.y),
                           bflo(ju.z), bfhi(ju.z), bflo(ju.w), bfhi(ju.w)};
#pragma unroll
      for (int b = 0; b < 8; ++b) {
        d[0][b] += __builtin_fabsf(ja[b] - vi.x);
        d[1][b] += __builtin_fabsf(ja[b] - vi.y);
      }
    }
  }

  float s[2];
#pragma unroll
  for (int a = 0; a < 2; ++a) {
    const int ia = ibase + (is << 1) + a;
    float t = 0.0f;
#pragma unroll
    for (int b = 0; b < 8; ++b) {
      const int j = (jg << 3) + b;
      const float e = __expf(-d[a][b]);
      t += (j == ia) ? 0.0f : e;               // skip self-term exactly
    }
    s[a] = t;
  }

  __syncthreads();
  float* red = reinterpret_cast<float*>(MjB);  // red[i_local 32][jg 32], stride 33
  red[((is << 1) + 0) * 33 + jg] = s[0];
  red[((is << 1) + 1) * 33 + jg] = s[1];
  __syncthreads();
  if (tid < 32) {
    float t = 0.0f;
#pragma unroll
    for (int g = 0; g < 32; ++g) t += red[tid * 33 + g];
    out[(ibase + tid) * 64 + o] = t;           // self-term already excluded
  }
}

extern "C" void kernel_launch(void* const* d_in, const int* in_sizes, int n_in,
                              void* d_out, int out_size, void* d_ws, size_t ws_size,
                              hipStream_t stream) {
  const float* x = (const float*)d_in[0];   // [256,512]
  const float* T = (const float*)d_in[1];   // [512,75,64]
  float* out = (float*)d_out;               // [256,64]

  float* Mt2 = (float*)d_ws;                // 2 x 4,915,200 B

  md_gemm_direct<<<dim3(75, 4, 2), 256, 0, stream>>>(x, T, Mt2);
  md_pair4<<<512, 512, 0, stream>>>(Mt2, out);
}